// Round 11
// baseline (11520.367 us; speedup 1.0000x reference)
//
#include <hip/hip_runtime.h>
#include <cmath>

#define B 64
#define S 4096
#define NI 16
#define H 128
#define F 144   // H + NI
#define CH 16   // timesteps per chunk (gi tile, handoff, flush)
#define NCH (S / CH)
#define GIP 129 // padded gi row

typedef _Float16 h2   __attribute__((ext_vector_type(2)));
typedef _Float16 h8   __attribute__((ext_vector_type(8)));
typedef float    f4v  __attribute__((ext_vector_type(4)));
typedef unsigned long long u64;
typedef u64 u64x2 __attribute__((ext_vector_type(2)));

__device__ __forceinline__ float rcp_fast(float x) { return __builtin_amdgcn_rcpf(x); }
__device__ __forceinline__ float sigf(float x) {
    return rcp_fast(1.0f + __expf(-x));
}
// tanh(x) = 2*sigmoid(2x) - 1
__device__ __forceinline__ float tanh_fast(float x) {
    const float e = __expf(-2.0f * x);
    return fmaf(2.0f, rcp_fast(1.0f + e), -1.0f);
}
__device__ __forceinline__ h2 cvt2(float a, float b) {
    h2 r; r[0] = (_Float16)a; r[1] = (_Float16)b; return r;
}
// convert 8 consecutive fp32 -> 4 packed half2 regs
__device__ __forceinline__ void cvt8(const float* p, h2* w) {
    const float4 f0 = ((const float4*)p)[0];
    const float4 f1 = ((const float4*)p)[1];
    w[0] = cvt2(f0.x, f0.y); w[1] = cvt2(f0.z, f0.w);
    w[2] = cvt2(f1.x, f1.y); w[3] = cvt2(f1.z, f1.w);
}
// convert 8 consecutive fp32 -> h8
__device__ __forceinline__ h8 cvt8v(const float* p) {
    const float4 f0 = ((const float4*)p)[0];
    const float4 f1 = ((const float4*)p)[1];
    h8 r;
    r[0] = (_Float16)f0.x; r[1] = (_Float16)f0.y;
    r[2] = (_Float16)f0.z; r[3] = (_Float16)f0.w;
    r[4] = (_Float16)f1.x; r[5] = (_Float16)f1.y;
    r[6] = (_Float16)f1.z; r[7] = (_Float16)f1.w;
    return r;
}
__device__ __forceinline__ void pin_h2(h2& v) {
    int t = __builtin_bit_cast(int, v);
    asm volatile("" : "+v"(t));
    v = __builtin_bit_cast(h2, t);
}
__device__ __forceinline__ void pin_f(float& v) { asm volatile("" : "+v"(v)); }
__device__ __forceinline__ void pin_h8(h8& v) {
    u64x2 t = __builtin_bit_cast(u64x2, v);
    u64 a = t[0], b = t[1];
    asm volatile("" : "+v"(a), "+v"(b));
    t[0] = a; t[1] = b;
    v = __builtin_bit_cast(h8, t);
}
__device__ __forceinline__ f4v mfma16(h8 a, h8 b, f4v c) {
    return __builtin_amdgcn_mfma_f32_16x16x32_f16(a, b, c, 0, 0, 0);
}

// ---- intra-block monotonic-counter sync (LDS, workgroup scope) ----
// Fast path: pure load spin (no sleep quantization); sleep only if starved.
__device__ __forceinline__ void poll_ge(int* p, int v) {
    int spins = 0;
    while (__hip_atomic_load(p, __ATOMIC_ACQUIRE, __HIP_MEMORY_SCOPE_WORKGROUP) < v) {
        if (++spins > 256) __builtin_amdgcn_s_sleep(1);
        if (spins > (1 << 20)) break;   // safety: wrong answer, not a hang
    }
}
__device__ __forceinline__ void publish(int* p, int v) {
    __hip_atomic_store(p, v, __ATOMIC_RELEASE, __HIP_MEMORY_SCOPE_WORKGROUP);
}

// ---- cross-XCD-safe handoff primitives (agent scope) ----
__device__ __forceinline__ void store_y0(void* p, uint2 v) {
    __hip_atomic_store((u64*)p, __builtin_bit_cast(u64, v),
                       __ATOMIC_RELAXED, __HIP_MEMORY_SCOPE_AGENT);
}
__device__ __forceinline__ h8 load_y0_h8(const _Float16* p) {
    u64x2 v;
    v[0] = __hip_atomic_load((const u64*)p,     __ATOMIC_RELAXED, __HIP_MEMORY_SCOPE_AGENT);
    v[1] = __hip_atomic_load((const u64*)p + 1, __ATOMIC_RELAXED, __HIP_MEMORY_SCOPE_AGENT);
    return __builtin_bit_cast(h8, v);
}
__device__ __forceinline__ void wait_flag(int* f) {
    int spins = 0;
    while (__hip_atomic_load(f, __ATOMIC_ACQUIRE, __HIP_MEMORY_SCOPE_AGENT) == 0) {
        __builtin_amdgcn_s_sleep(8);
        if (++spins > (1 << 17)) break;
    }
}
__device__ __forceinline__ void post_flag(int* f) {
    __hip_atomic_store(f, 1, __ATOMIC_RELEASE, __HIP_MEMORY_SCOPE_AGENT);
}

// ---------------------------------------------------------------------------
// Barrier-free GRU, latency-hidden handshake. 128 blocks x 256 threads.
// blockIdx even = layer-0 block, odd = layer-1 block (batch = blockIdx>>1).
// waves 0-1: recurrence, 1 unit/lane, full-K weights in VGPRs. Step order:
//   [gi read] -> own-half dots (h[t-1] own half, regs) -> poll partner ->
//   read partner half -> partner-half dots -> gates -> write h[t] ->
//   publish -> read own half of h[t] (intra-wave, no sync).
//   The cross-wave LDS round trip is hidden under ~96 fdot2 of own-half work.
// waves 2-3: helpers (chunk-granular, r10-proven): gi via MFMA, out-ring
//   flush, inter-block flags.
// Ring safety (depth-2 sH): partner's publish(t) follows its read of my-half
// h[t-2] (program order), so my poll ot>=t before writing slot t&1 closes
// the overwrite hazard; my write of h[t-1]'s slot precedes partner's read
// via its poll me>=t.
// ---------------------------------------------------------------------------
__global__ __launch_bounds__(256, 1)
void gru_poll(const float* __restrict__ x,
              const float* __restrict__ w_ih0, const float* __restrict__ w_hh0,
              const float* __restrict__ b_ih0, const float* __restrict__ b_hh0,
              const float* __restrict__ w_ih1, const float* __restrict__ w_hh1,
              const float* __restrict__ b_ih1, const float* __restrict__ b_hh1,
              _Float16* __restrict__ hbuf, int* __restrict__ flags)
{
    __shared__ __align__(16) _Float16 sH[2][H];            // h ping-pong
    __shared__ __align__(16) float    sGi[2][CH][3][GIP];  // 49.5 KB
    __shared__ __align__(16) _Float16 sO[2][CH][H];        // out ring (y0/h1)
    __shared__ int sCnt[2];      // rec step counters
    __shared__ int sGiDone[2];   // per-helper-wave gi chunks done
    __shared__ int sFlush[2];    // per-helper-wave chunks flushed

    const int tid  = threadIdx.x;
    const int wave = tid >> 6;
    const int lane = tid & 63;
    const int b    = blockIdx.x >> 1;
    const bool producer = (blockIdx.x & 1) == 0;

    _Float16* yb = hbuf + (size_t)b * S * H;   // y0 stream (L1: h1 out in place)
    int*      fb = flags + b * NCH;

    if (tid == 0) {
        sCnt[0] = 0; sCnt[1] = 0;
        sGiDone[0] = 0; sGiDone[1] = 0;
        sFlush[0] = 0; sFlush[1] = 0;
    }
    if (wave < 2) {   // zero both h slots (own half each)
        const int j0 = 64 * wave + lane;
        sH[0][j0] = (_Float16)0.0f;
        sH[1][j0] = (_Float16)0.0f;
    }
    __syncthreads();   // once, before the loop

    if (wave < 2) {
        // ================= recurrence pair =================
        const int j = 64 * wave + lane;            // unit 0..127
        const float* Whh = producer ? w_hh0 : w_hh1;
        const float* Bhh = producer ? b_hh0 : b_hh1;

        h2 w[192];   // [0..63] r, [64..127] z, [128..191] hn — full K
#pragma unroll
        for (int g = 0; g < 3; g++)
#pragma unroll
            for (int i = 0; i < 16; i++)
                cvt8(Whh + (size_t)(g * H + j) * H + 8 * i, &w[g * 64 + 4 * i]);
        float b_hn = Bhh[2 * H + j];
#pragma unroll
        for (int i = 0; i < 192; i++) pin_h2(w[i]);
        pin_f(b_hn);

        // own-half h[t-1] fragments (own K range = [64*wave, 64*wave+64))
        float4 hov[8];
#pragma unroll
        for (int i = 0; i < 8; i++) hov[i] = make_float4(0.f, 0.f, 0.f, 0.f);
        float hprev = 0.0f;

        int* me = &sCnt[wave];
        int* ot = &sCnt[wave ^ 1];
        const int wo = 32 * wave;            // own-half h2-weight offset
        const int po = 32 * (wave ^ 1);      // partner-half offset

        for (int t = 0; t < S; t++) {
            const int c = t >> 4, tw = t & 15;
            if (tw == 0) {          // gi chunk ready? (subsumes flush gate)
                poll_ge(&sGiDone[0], c + 1);
                poll_ge(&sGiDone[1], c + 1);
            }
            const float gr = sGi[c & 1][tw][0][j];
            const float gz = sGi[c & 1][tw][1][j];
            const float gn = sGi[c & 1][tw][2][j];

            // ---- own-half dots first (no cross-wave dependency) ----
            float ar = 0.f, az = 0.f, an = 0.f;
#pragma unroll
            for (int i = 0; i < 8; i++) {
                const float4 q = hov[i];
                const h2 p0 = __builtin_bit_cast(h2, q.x);
                const h2 p1 = __builtin_bit_cast(h2, q.y);
                const h2 p2 = __builtin_bit_cast(h2, q.z);
                const h2 p3 = __builtin_bit_cast(h2, q.w);
                ar = __builtin_amdgcn_fdot2(p0, w[wo+4*i+0],     ar, false);
                ar = __builtin_amdgcn_fdot2(p1, w[wo+4*i+1],     ar, false);
                ar = __builtin_amdgcn_fdot2(p2, w[wo+4*i+2],     ar, false);
                ar = __builtin_amdgcn_fdot2(p3, w[wo+4*i+3],     ar, false);
                az = __builtin_amdgcn_fdot2(p0, w[64+wo+4*i+0],  az, false);
                az = __builtin_amdgcn_fdot2(p1, w[64+wo+4*i+1],  az, false);
                az = __builtin_amdgcn_fdot2(p2, w[64+wo+4*i+2],  az, false);
                az = __builtin_amdgcn_fdot2(p3, w[64+wo+4*i+3],  az, false);
                an = __builtin_amdgcn_fdot2(p0, w[128+wo+4*i+0], an, false);
                an = __builtin_amdgcn_fdot2(p1, w[128+wo+4*i+1], an, false);
                an = __builtin_amdgcn_fdot2(p2, w[128+wo+4*i+2], an, false);
                an = __builtin_amdgcn_fdot2(p3, w[128+wo+4*i+3], an, false);
            }
            // ---- partner half: poll (long since published), read, dots ----
            poll_ge(ot, t);     // partner wrote its half of h[t-1]
            const float4* pb = (const float4*)&sH[(t & 1) ^ 1][64 * (wave ^ 1)];
#pragma unroll
            for (int i = 0; i < 8; i++) {
                const float4 q = pb[i];
                const h2 p0 = __builtin_bit_cast(h2, q.x);
                const h2 p1 = __builtin_bit_cast(h2, q.y);
                const h2 p2 = __builtin_bit_cast(h2, q.z);
                const h2 p3 = __builtin_bit_cast(h2, q.w);
                ar = __builtin_amdgcn_fdot2(p0, w[po+4*i+0],     ar, false);
                ar = __builtin_amdgcn_fdot2(p1, w[po+4*i+1],     ar, false);
                ar = __builtin_amdgcn_fdot2(p2, w[po+4*i+2],     ar, false);
                ar = __builtin_amdgcn_fdot2(p3, w[po+4*i+3],     ar, false);
                az = __builtin_amdgcn_fdot2(p0, w[64+po+4*i+0],  az, false);
                az = __builtin_amdgcn_fdot2(p1, w[64+po+4*i+1],  az, false);
                az = __builtin_amdgcn_fdot2(p2, w[64+po+4*i+2],  az, false);
                az = __builtin_amdgcn_fdot2(p3, w[64+po+4*i+3],  az, false);
                an = __builtin_amdgcn_fdot2(p0, w[128+po+4*i+0], an, false);
                an = __builtin_amdgcn_fdot2(p1, w[128+po+4*i+1], an, false);
                an = __builtin_amdgcn_fdot2(p2, w[128+po+4*i+2], an, false);
                an = __builtin_amdgcn_fdot2(p3, w[128+po+4*i+3], an, false);
            }
            const float r  = sigf(ar + gr);
            const float z  = sigf(az + gz);
            const float n  = tanh_fast(gn + r * (an + b_hn));
            const float hn = n + z * (hprev - n);
            hprev = hn;

            sH[t & 1][j]     = (_Float16)hn;
            sO[c & 1][tw][j] = (_Float16)hn;
            publish(me, t + 1);          // release: orders the two ds_writes
            // own half of h[t]: intra-wave write->read, no cross-wave sync
            const float4* ob = (const float4*)&sH[t & 1][64 * wave];
#pragma unroll
            for (int i = 0; i < 8; i++) hov[i] = ob[i];
        }
    } else {
        // ================= helper pair (chunk-granular, r10-proven) =========
        const int hw = wave - 2;           // 0 or 1
        const int nl = lane & 15;          // A row (timestep) / B col n
        const int q  = lane >> 4;          // k-group / C row group
        const float* xb = x + (size_t)b * S * NI;

        h8 Bf4[12][4];   // consumer: W_ih1 fragments (K=128)
        h8 Bf1[12];      // producer: W_ih0 fragments (K=16)
        float bias[12];
#pragma unroll
        for (int tt = 0; tt < 12; tt++) {
            const int n = 16 * (hw * 12 + tt) + nl;
            if (producer) {
                if (q < 2) Bf1[tt] = cvt8v(w_ih0 + (size_t)n * NI + 8 * q);
                else { h8 zz = {}; Bf1[tt] = zz; }
                pin_h8(Bf1[tt]);
                bias[tt] = b_ih0[n] + (n < 2 * H ? b_hh0[n] : 0.0f);
            } else {
                const float* wr = w_ih1 + (size_t)n * H;
#pragma unroll
                for (int kc = 0; kc < 4; kc++) {
                    Bf4[tt][kc] = cvt8v(wr + 32 * kc + 8 * q);
                    pin_h8(Bf4[tt][kc]);
                }
                bias[tt] = b_ih1[n] + (n < 2 * H ? b_hh1[n] : 0.0f);
            }
            pin_f(bias[tt]);
        }

        for (int c = 0; c < NCH; c++) {
            if (c >= 2) {
                // rec finished chunk c-2: sO[c&1] complete, sGi[c&1] consumed
                poll_ge(&sCnt[0], 16 * (c - 1));
                poll_ge(&sCnt[1], 16 * (c - 1));
                const int k = c - 2;
                const uint2* src = (const uint2*)&sO[c & 1][0][0];
#pragma unroll
                for (int e = 0; e < 4; e++) {
                    const int idx = hw * 256 + 64 * e + lane;
                    const uint2 v = src[idx];
                    if (producer)
                        store_y0((char*)(yb + (size_t)k * CH * H) + 8 * idx, v);
                    else
                        *(uint2*)((char*)(yb + (size_t)k * CH * H) + 8 * idx) = v;
                }
                if (producer) {
                    publish(&sFlush[hw], c - 1);   // release waits own vmcnt
                    if (hw == 0) {
                        poll_ge(&sFlush[1], c - 1);
                        if (lane == 0) post_flag(fb + k);
                    }
                }
            }
            // gi for chunk c
            f4v accs[12];
#pragma unroll
            for (int tt = 0; tt < 12; tt++) { f4v zz = {0.f,0.f,0.f,0.f}; accs[tt] = zz; }
            if (producer) {
                h8 A;
                if (q < 2) A = cvt8v(xb + (size_t)(16 * c + nl) * NI + 8 * q);
                else { h8 zz = {}; A = zz; }
#pragma unroll
                for (int tt = 0; tt < 12; tt++) accs[tt] = mfma16(A, Bf1[tt], accs[tt]);
            } else {
                if (lane == 0) wait_flag(fb + c);
                const _Float16* yr = yb + (size_t)(16 * c + nl) * H;
                h8 A[4];
#pragma unroll
                for (int kc = 0; kc < 4; kc++)
                    A[kc] = load_y0_h8(yr + 32 * kc + 8 * q);
#pragma unroll
                for (int kc = 0; kc < 4; kc++)
#pragma unroll
                    for (int tt = 0; tt < 12; tt++)
                        accs[tt] = mfma16(A[kc], Bf4[tt][kc], accs[tt]);
            }
            float* gp = &sGi[c & 1][0][0][0];
#pragma unroll
            for (int tt = 0; tt < 12; tt++) {
                const int n = 16 * (hw * 12 + tt) + nl;
                const int g = n >> 7, jj = n & 127;
#pragma unroll
                for (int r = 0; r < 4; r++)
                    gp[((4 * q + r) * 3 + g) * GIP + jj] = accs[tt][r] + bias[tt];
            }
            publish(&sGiDone[hw], c + 1);   // release: orders the LDS writes
        }
        // tail: flush chunks NCH-2, NCH-1
        for (int k = NCH - 2; k < NCH; k++) {
            poll_ge(&sCnt[0], 16 * (k + 1));
            poll_ge(&sCnt[1], 16 * (k + 1));
            const uint2* src = (const uint2*)&sO[k & 1][0][0];
#pragma unroll
            for (int e = 0; e < 4; e++) {
                const int idx = hw * 256 + 64 * e + lane;
                const uint2 v = src[idx];
                if (producer)
                    store_y0((char*)(yb + (size_t)k * CH * H) + 8 * idx, v);
                else
                    *(uint2*)((char*)(yb + (size_t)k * CH * H) + 8 * idx) = v;
            }
            if (producer) {
                publish(&sFlush[hw], k + 1);
                if (hw == 0) {
                    poll_ge(&sFlush[1], k + 1);
                    if (lane == 0) post_flag(fb + k);
                }
            }
        }
    }
}

// ---------------------------------------------------------------------------
// MFMA MLP head. 512 blocks x 256 threads (4 independent waves, no barriers).
// ---------------------------------------------------------------------------
__global__ __launch_bounds__(256, 2)
void head_mfma(const _Float16* __restrict__ h1, const float* __restrict__ x,
               const float* __restrict__ w1, const float* __restrict__ b1,
               const float* __restrict__ w2, const float* __restrict__ b2,
               float* __restrict__ inc)
{
    const int wave = threadIdx.x >> 6;
    const int lane = threadIdx.x & 63;
    const int nl   = lane & 15;
    const int q    = lane >> 4;

    h8 Bf[4][5];
    float b1v[4], w2v[4];
#pragma unroll
    for (int t = 0; t < 4; t++) {
        const int n = 16 * t + nl;
        const float* wr = w1 + (size_t)n * F;
#pragma unroll
        for (int c = 0; c < 4; c++)
            Bf[t][c] = cvt8v(wr + 32 * c + 8 * q);
        if (q < 2) Bf[t][4] = cvt8v(wr + 128 + 8 * q);
        else { h8 z = {};
               Bf[t][4] = z; }
        b1v[t] = b1[n];
        w2v[t] = w2[n];
    }
    const float b2v = b2[0];

    const int gw = blockIdx.x * 4 + wave;

    for (int it = 0; it < 8; it++) {
        const int row0 = (gw * 8 + it) * 16;
        const int rm   = row0 + nl;

        const _Float16* hp = h1 + (size_t)rm * H;
        h8 A0 = *(const h8*)(hp + 8 * q);
        h8 A1 = *(const h8*)(hp + 32 + 8 * q);
        h8 A2 = *(const h8*)(hp + 64 + 8 * q);
        h8 A3 = *(const h8*)(hp + 96 + 8 * q);
        h8 A4;
        if (q < 2) A4 = cvt8v(x + (size_t)rm * NI + 8 * q);
        else { h8 z = {}; A4 = z; }

        f4v acc0 = {0.f,0.f,0.f,0.f}, acc1 = {0.f,0.f,0.f,0.f};
        f4v acc2 = {0.f,0.f,0.f,0.f}, acc3 = {0.f,0.f,0.f,0.f};
        acc0 = mfma16(A0, Bf[0][0], acc0); acc1 = mfma16(A0, Bf[1][0], acc1);
        acc2 = mfma16(A0, Bf[2][0], acc2); acc3 = mfma16(A0, Bf[3][0], acc3);
        acc0 = mfma16(A1, Bf[0][1], acc0); acc1 = mfma16(A1, Bf[1][1], acc1);
        acc2 = mfma16(A1, Bf[2][1], acc2); acc3 = mfma16(A1, Bf[3][1], acc3);
        acc0 = mfma16(A2, Bf[0][2], acc0); acc1 = mfma16(A2, Bf[1][2], acc1);
        acc2 = mfma16(A2, Bf[2][2], acc2); acc3 = mfma16(A2, Bf[3][2], acc3);
        acc0 = mfma16(A3, Bf[0][3], acc0); acc1 = mfma16(A3, Bf[1][3], acc1);
        acc2 = mfma16(A3, Bf[2][3], acc2); acc3 = mfma16(A3, Bf[3][3], acc3);
        acc0 = mfma16(A4, Bf[0][4], acc0); acc1 = mfma16(A4, Bf[1][4], acc1);
        acc2 = mfma16(A4, Bf[2][4], acc2); acc3 = mfma16(A4, Bf[3][4], acc3);

        float rs[4];
#pragma unroll
        for (int r = 0; r < 4; r++) {
            rs[r] = fmaxf(acc0[r] + b1v[0], 0.f) * w2v[0]
                  + fmaxf(acc1[r] + b1v[1], 0.f) * w2v[1]
                  + fmaxf(acc2[r] + b1v[2], 0.f) * w2v[2]
                  + fmaxf(acc3[r] + b1v[3], 0.f) * w2v[3];
        }
#pragma unroll
        for (int off = 1; off < 16; off <<= 1) {
#pragma unroll
            for (int r = 0; r < 4; r++)
                rs[r] += __shfl_xor(rs[r], off, 64);
        }
        if (nl == 0) {
            float4 o;
            o.x = tanh_fast(rs[0] + b2v) * 0.125f;
            o.y = tanh_fast(rs[1] + b2v) * 0.125f;
            o.z = tanh_fast(rs[2] + b2v) * 0.125f;
            o.w = tanh_fast(rs[3] + b2v) * 0.125f;
            *(float4*)(inc + row0 + 4 * q) = o;
        }
    }
}

// ---------------------------------------------------------------------------
// Inclusive cumsum over S per batch + initial offset. One block per batch.
// ---------------------------------------------------------------------------
__global__ __launch_bounds__(256)
void cumsum_kernel(const float* __restrict__ inc, const float* __restrict__ init,
                   float* __restrict__ out)
{
    __shared__ float sW[4];
    const int b = blockIdx.x;
    const int tid = threadIdx.x;
    const int lane = tid & 63;
    const int wid = tid >> 6;

    const float* ib = inc + (size_t)b * S;
    float v[16];
#pragma unroll
    for (int i = 0; i < 16; i++) v[i] = ib[tid * 16 + i];

    float run = 0.f;
#pragma unroll
    for (int i = 0; i < 16; i++) { run += v[i]; v[i] = run; }

    float t = run;
#pragma unroll
    for (int off = 1; off < 64; off <<= 1) {
        float u = __shfl_up(t, off, 64);
        if (lane >= off) t += u;
    }
    const float excl = t - run;
    if (lane == 63) sW[wid] = t;
    __syncthreads();

    float wo = 0.f;
#pragma unroll
    for (int w = 0; w < 4; w++) if (w < wid) wo += sW[w];

    const float prefix = wo + excl + init[0];
    float* ob = out + (size_t)b * S;
#pragma unroll
    for (int i = 0; i < 16; i++) ob[tid * 16 + i] = prefix + v[i];
}

// ---------------------------------------------------------------------------
extern "C" void kernel_launch(void* const* d_in, const int* in_sizes, int n_in,
                              void* d_out, int out_size, void* d_ws, size_t ws_size,
                              hipStream_t stream)
{
    (void)in_sizes; (void)n_in; (void)out_size; (void)ws_size;
    const float* x     = (const float*)d_in[0];
    const float* w_ih0 = (const float*)d_in[1];
    const float* w_hh0 = (const float*)d_in[2];
    const float* b_ih0 = (const float*)d_in[3];
    const float* b_hh0 = (const float*)d_in[4];
    const float* w_ih1 = (const float*)d_in[5];
    const float* w_hh1 = (const float*)d_in[6];
    const float* b_ih1 = (const float*)d_in[7];
    const float* b_hh1 = (const float*)d_in[8];
    const float* w1    = (const float*)d_in[9];
    const float* b1    = (const float*)d_in[10];
    const float* w2    = (const float*)d_in[11];
    const float* b2    = (const float*)d_in[12];
    const float* init  = (const float*)d_in[13];
    float* out = (float*)d_out;

    _Float16* hbuf = (_Float16*)d_ws;                                   // 64 MB fp16
    float* incbuf  = (float*)((char*)d_ws + (size_t)B * S * H * 2);     // 1 MB
    int* flags     = (int*)((char*)d_ws + (size_t)B * S * H * 2
                                        + (size_t)B * S * 4);           // 64 KB

    hipMemsetAsync(flags, 0, (size_t)B * NCH * sizeof(int), stream);

    hipLaunchKernelGGL(gru_poll, dim3(2 * B), dim3(256), 0, stream,
                       x, w_ih0, w_hh0, b_ih0, b_hh0,
                       w_ih1, w_hh1, b_ih1, b_hh1, hbuf, flags);
    hipLaunchKernelGGL(head_mfma, dim3(512), dim3(256), 0, stream,
                       hbuf, x, w1, b1, w2, b2, incbuf);
    hipLaunchKernelGGL(cumsum_kernel, dim3(B), dim3(256), 0, stream,
                       incbuf, init, out);
}

// Round 12
// 2495.224 us; speedup vs baseline: 4.6170x; 4.6170x over previous
//
#include <hip/hip_runtime.h>
#include <cmath>

#define B 64
#define S 4096
#define NI 16
#define H 128
#define F 144   // H + NI
#define CH 16   // timesteps per chunk (x staging, y0 handoff, h1 flush)
#define NCH (S / CH)
#define GIP 129 // padded gi row

typedef _Float16 h2   __attribute__((ext_vector_type(2)));
typedef _Float16 h4v  __attribute__((ext_vector_type(4)));
typedef _Float16 h8   __attribute__((ext_vector_type(8)));
typedef float    f4v  __attribute__((ext_vector_type(4)));
typedef unsigned long long u64;
typedef u64 u64x2 __attribute__((ext_vector_type(2)));

__device__ __forceinline__ float rcp_fast(float x) { return __builtin_amdgcn_rcpf(x); }
__device__ __forceinline__ float sigf(float x) {
    return rcp_fast(1.0f + __expf(-x));
}
// tanh(x) = 2*sigmoid(2x) - 1
__device__ __forceinline__ float tanh_fast(float x) {
    const float e = __expf(-2.0f * x);
    return fmaf(2.0f, rcp_fast(1.0f + e), -1.0f);
}
// all 4 lanes of each quad end with the 4-lane sum
__device__ __forceinline__ float quad_reduce(float v) {
    int t1 = __builtin_amdgcn_mov_dpp(__float_as_int(v), 0xB1, 0xf, 0xf, true); // xor 1
    v += __int_as_float(t1);
    int t2 = __builtin_amdgcn_mov_dpp(__float_as_int(v), 0x4E, 0xf, 0xf, true); // xor 2
    v += __int_as_float(t2);
    return v;
}
// both lanes of each pair end with the 2-lane sum
__device__ __forceinline__ float pair_reduce(float v) {
    int t1 = __builtin_amdgcn_mov_dpp(__float_as_int(v), 0xB1, 0xf, 0xf, true); // xor 1
    v += __int_as_float(t1);
    return v;
}
__device__ __forceinline__ h2 cvt2(float a, float b) {
    h2 r; r[0] = (_Float16)a; r[1] = (_Float16)b; return r;
}
// convert 8 consecutive fp32 -> 4 packed half2 regs
__device__ __forceinline__ void cvt8(const float* p, h2* w) {
    const float4 f0 = ((const float4*)p)[0];
    const float4 f1 = ((const float4*)p)[1];
    w[0] = cvt2(f0.x, f0.y); w[1] = cvt2(f0.z, f0.w);
    w[2] = cvt2(f1.x, f1.y); w[3] = cvt2(f1.z, f1.w);
}
// convert 8 consecutive fp32 -> h8
__device__ __forceinline__ h8 cvt8v(const float* p) {
    const float4 f0 = ((const float4*)p)[0];
    const float4 f1 = ((const float4*)p)[1];
    h8 r;
    r[0] = (_Float16)f0.x; r[1] = (_Float16)f0.y;
    r[2] = (_Float16)f0.z; r[3] = (_Float16)f0.w;
    r[4] = (_Float16)f1.x; r[5] = (_Float16)f1.y;
    r[6] = (_Float16)f1.z; r[7] = (_Float16)f1.w;
    return r;
}
__device__ __forceinline__ void pin_h2(h2& v) {
    int t = __builtin_bit_cast(int, v);
    asm volatile("" : "+v"(t));
    v = __builtin_bit_cast(h2, t);
}
__device__ __forceinline__ void pin_f(float& v) {
    asm volatile("" : "+v"(v));
}
__device__ __forceinline__ void pin_h8(h8& v) {
    u64x2 t = __builtin_bit_cast(u64x2, v);
    u64 a = t[0], b = t[1];
    asm volatile("" : "+v"(a), "+v"(b));
    t[0] = a; t[1] = b;
    v = __builtin_bit_cast(h8, t);
}
__device__ __forceinline__ f4v mfma16(h8 a, h8 b, f4v c) {
    return __builtin_amdgcn_mfma_f32_16x16x32_f16(a, b, c, 0, 0, 0);
}

// ---- cross-XCD-safe handoff primitives (agent scope -> coherence point) ----
__device__ __forceinline__ void store_y0(void* p, uint2 v) {
    __hip_atomic_store((u64*)p, __builtin_bit_cast(u64, v),
                       __ATOMIC_RELAXED, __HIP_MEMORY_SCOPE_AGENT);
}
__device__ __forceinline__ h8 load_y0_h8(const _Float16* p) {
    u64x2 v;
    v[0] = __hip_atomic_load((const u64*)p,     __ATOMIC_RELAXED, __HIP_MEMORY_SCOPE_AGENT);
    v[1] = __hip_atomic_load((const u64*)p + 1, __ATOMIC_RELAXED, __HIP_MEMORY_SCOPE_AGENT);
    return __builtin_bit_cast(h8, v);
}
// Bounded spin (WITH s_sleep yield — r11 showed a sleepless spin starves the
// co-resident wave being waited on): stall becomes a wrong answer, not a hang.
__device__ __forceinline__ void wait_flag(int* f) {
    int spins = 0;
    while (__hip_atomic_load(f, __ATOMIC_ACQUIRE, __HIP_MEMORY_SCOPE_AGENT) == 0) {
        __builtin_amdgcn_s_sleep(8);
        if (++spins > (1 << 17)) break;
    }
}
__device__ __forceinline__ void post_flag(int* f) {
    __hip_atomic_store(f, 1, __ATOMIC_RELEASE, __HIP_MEMORY_SCOPE_AGENT);
}

// ---------------------------------------------------------------------------
// Layer-split pipelined GRU (session optimum, verified r3/r7/r9 at ~2.5 ms).
// 128 blocks x 512 threads.
// blockIdx even: layer-0 producer for batch (blockIdx>>1), quad K-split over
// all 512 threads (x-dots inline, x chunk-staged, y0 flushed via agent stores).
// blockIdx odd : layer-1 consumer:
//   waves 0-3: recurrence ONLY (h . W_hh1, pair K-split) + gates, reading the
//              input projection gi[t] from LDS (3 scalar reads).
//   waves 4-7: MFMA helpers — per 16-step chunk, load next y0 chunk and
//              compute gi = y0 . W_ih1 + biases, and flush h1 chunks.
// All waves execute identical __syncthreads counts (uniform loop).
// Session notes baked in:
//  - plain __syncthreads is optimal (r8: asm light-barriers/setprio -10%)
//  - poll-based sync loses to the barrier (r10/r11)
//  - per-step cost ~1450 cy is exchange-latency + gate-chain skeleton; no
//    counter-visible pipe is saturated (VALU 25%, MFMA 0.4%, HBM 0.9%).
// ---------------------------------------------------------------------------
__global__ __launch_bounds__(512, 2)
void gru_pipe(const float* __restrict__ x,
              const float* __restrict__ w_ih0, const float* __restrict__ w_hh0,
              const float* __restrict__ b_ih0, const float* __restrict__ b_hh0,
              const float* __restrict__ w_ih1, const float* __restrict__ w_hh1,
              const float* __restrict__ b_ih1, const float* __restrict__ b_hh1,
              _Float16* __restrict__ hbuf, int* __restrict__ flags)
{
    const int tid = threadIdx.x;
    const int b = blockIdx.x >> 1;
    const bool producer = (blockIdx.x & 1) == 0;

    if (producer) {
        // ================= L0 producer =================
        const int j = tid >> 2;     // output unit 0..127
        const int m = tid & 3;      // K quarter

        __shared__ __align__(16) _Float16 sH0[2][H];
        __shared__ __align__(16) _Float16 sX[2][CH][NI];
        __shared__ __align__(16) _Float16 sYo[2][CH][H];

        h2 wh[48];   // [0..15] r, [16..31] z, [32..47] hn   (w_hh0)
        h2 wx[6];    // [0..1] r, [2..3] z, [4..5] in        (w_ih0, quarter of I)
#pragma unroll
        for (int g = 0; g < 3; g++) {
            const float* wr = w_hh0 + (size_t)(g * H + j) * H;
#pragma unroll
            for (int i = 0; i < 4; i++) {
                const int f = (i + m) & 3;
                cvt8(wr + 32 * m + 8 * f, &wh[g * 16 + 4 * i]);
            }
            const float4 wv = *(const float4*)(w_ih0 + (size_t)(g * H + j) * NI + 4 * m);
            wx[g * 2 + 0] = cvt2(wv.x, wv.y);
            wx[g * 2 + 1] = cvt2(wv.z, wv.w);
        }
        float b_r  = b_ih0[j]       + b_hh0[j];
        float b_z  = b_ih0[H + j]   + b_hh0[H + j];
        float b_in = b_ih0[2*H + j];
        float b_hn = b_hh0[2*H + j];
#pragma unroll
        for (int i = 0; i < 48; i++) pin_h2(wh[i]);
#pragma unroll
        for (int i = 0; i < 6; i++) pin_h2(wx[i]);
        pin_f(b_r); pin_f(b_z); pin_f(b_in); pin_f(b_hn);

        const float* xb = x + (size_t)b * S * NI;
        _Float16*    yb = hbuf + (size_t)b * S * H;
        int*         fb = flags + b * NCH;

        float4 xreg = {0.f, 0.f, 0.f, 0.f};
        if (tid < H) sH0[0][tid] = (_Float16)0.0f;
        if (tid < 64) {
            const float4 v = ((const float4*)xb)[tid];
            h4v p; p[0] = (_Float16)v.x; p[1] = (_Float16)v.y;
                   p[2] = (_Float16)v.z; p[3] = (_Float16)v.w;
            ((h4v*)&sX[0][0][0])[tid] = p;
            xreg = ((const float4*)(xb + CH * NI))[tid];
        }
        float hprev = 0.0f;
        __syncthreads();

        for (int k = 0; k <= S; k++) {
            const int cur = k & 1;
            const int c0  = k >> 4;
            const int tw  = k & (CH - 1);

            if (tw == 0 && k >= CH) {
                const int cp = c0 - 1;
                const uint2 v = ((const uint2*)&sYo[cp & 1][0][0])[tid];
                store_y0((char*)(yb + (size_t)cp * CH * H) + 8 * tid, v);
            }
            if (tw == 1 && k >= CH + 1 && tid == 0) post_flag(fb + (c0 - 1));

            if (k < S) {
                if (tw == 0 && tid < 64) {
                    const int cn = c0 + 1;
                    if (cn < NCH) {
                        h4v p; p[0] = (_Float16)xreg.x; p[1] = (_Float16)xreg.y;
                               p[2] = (_Float16)xreg.z; p[3] = (_Float16)xreg.w;
                        ((h4v*)&sX[cn & 1][0][0])[tid] = p;
                        if (cn + 1 < NCH)
                            xreg = ((const float4*)(xb + (size_t)(cn + 1) * CH * NI))[tid];
                    }
                }

                const float4* hv = (const float4*)&sH0[cur][0];
                float ar = 0.f, az = 0.f, ahn = 0.f;
#pragma unroll
                for (int i = 0; i < 4; i++) {
                    const int f = (i + m) & 3;               // addr stagger
                    const float4 q = hv[4 * m + f];
                    const h2 p0 = __builtin_bit_cast(h2, q.x);
                    const h2 p1 = __builtin_bit_cast(h2, q.y);
                    const h2 p2 = __builtin_bit_cast(h2, q.z);
                    const h2 p3 = __builtin_bit_cast(h2, q.w);
                    ar  = __builtin_amdgcn_fdot2(p0, wh[4*i+0],    ar,  false);
                    ar  = __builtin_amdgcn_fdot2(p1, wh[4*i+1],    ar,  false);
                    ar  = __builtin_amdgcn_fdot2(p2, wh[4*i+2],    ar,  false);
                    ar  = __builtin_amdgcn_fdot2(p3, wh[4*i+3],    ar,  false);
                    az  = __builtin_amdgcn_fdot2(p0, wh[16+4*i+0], az,  false);
                    az  = __builtin_amdgcn_fdot2(p1, wh[16+4*i+1], az,  false);
                    az  = __builtin_amdgcn_fdot2(p2, wh[16+4*i+2], az,  false);
                    az  = __builtin_amdgcn_fdot2(p3, wh[16+4*i+3], az,  false);
                    ahn = __builtin_amdgcn_fdot2(p0, wh[32+4*i+0], ahn, false);
                    ahn = __builtin_amdgcn_fdot2(p1, wh[32+4*i+1], ahn, false);
                    ahn = __builtin_amdgcn_fdot2(p2, wh[32+4*i+2], ahn, false);
                    ahn = __builtin_amdgcn_fdot2(p3, wh[32+4*i+3], ahn, false);
                }
                const float2 xq = *(const float2*)&sX[c0 & 1][tw][4 * m];
                const h2 x0 = __builtin_bit_cast(h2, xq.x);
                const h2 x1 = __builtin_bit_cast(h2, xq.y);
                float ain = 0.f;
                ar  = __builtin_amdgcn_fdot2(x0, wx[0], ar,  false);
                ar  = __builtin_amdgcn_fdot2(x1, wx[1], ar,  false);
                az  = __builtin_amdgcn_fdot2(x0, wx[2], az,  false);
                az  = __builtin_amdgcn_fdot2(x1, wx[3], az,  false);
                ain = __builtin_amdgcn_fdot2(x0, wx[4], ain, false);
                ain = __builtin_amdgcn_fdot2(x1, wx[5], ain, false);

                const float vr  = quad_reduce(ar)  + b_r;
                const float vz  = quad_reduce(az)  + b_z;
                const float vin = quad_reduce(ain) + b_in;
                const float vhn = quad_reduce(ahn) + b_hn;

                const float r  = sigf(vr);
                const float z  = sigf(vz);
                const float n  = tanh_fast(vin + r * vhn);
                const float hn = n + z * (hprev - n);
                hprev = hn;
                if (m == 0) {
                    sH0[cur ^ 1][j]     = (_Float16)hn;
                    sYo[c0 & 1][tw][j]  = (_Float16)hn;
                }
            }
            __syncthreads();
        }
        if (tid == 0) post_flag(fb + (NCH - 1));
    } else {
        // ================= L1 consumer: recurrence + MFMA gi-helpers =========
        __shared__ __align__(16) _Float16 sH1[2][H];          // 512 B
        __shared__ __align__(16) float    sGi[2][CH][3][GIP]; // 49.5 KB
        __shared__ __align__(16) _Float16 sHo[2][CH][H];      // 8 KB

        _Float16* yb = hbuf + (size_t)b * S * H;   // y0 in, h1 out (in place)
        int*      fb = flags + b * NCH;

        const bool isRec = (tid < 256);
        const int lane = tid & 63;
        // recurrence mapping (tid < 256)
        const int jr = (tid & 255) >> 1;   // output unit 0..127
        const int mr = tid & 1;            // K half
        // helper mapping (tid >= 256)
        const int wv = (tid >> 6) - 4;     // helper wave 0..3
        const int nl = lane & 15;          // A row (timestep) / B col n
        const int q  = lane >> 4;          // k-group / C row group

        h2 wc[96];          // recurrence: W_hh1, [0..31] r, [32..63] z, [64..95] hn
        float b_hn = 0.0f;
        h8 Bf[6][4];        // helper: stationary W_ih1 fragments
        float bias[6];
        h8 Apre[4];         // helper: prefetched A fragments

        if (isRec) {
#pragma unroll
            for (int g = 0; g < 3; g++) {
#pragma unroll
                for (int i = 0; i < 8; i++) {
                    const int ii = (i + 4 * mr) & 7;     // addr stagger
                    cvt8(w_hh1 + (size_t)(g * H + jr) * H + 64 * mr + 8 * ii,
                         &wc[g * 32 + 4 * i]);
                }
            }
            b_hn = b_hh1[2 * H + jr];
#pragma unroll
            for (int i = 0; i < 96; i++) pin_h2(wc[i]);
            pin_f(b_hn);
            if (tid < H) sH1[0][tid] = (_Float16)0.0f;
        } else {
#pragma unroll
            for (int tt = 0; tt < 6; tt++) {
                const int n = 16 * (wv * 6 + tt) + nl;
                const float* wr = w_ih1 + (size_t)n * H;
#pragma unroll
                for (int kc = 0; kc < 4; kc++)
                    Bf[tt][kc] = cvt8v(wr + 32 * kc + 8 * q);
                bias[tt] = b_ih1[n] + (n < 2 * H ? b_hh1[n] : 0.0f);
            }
#pragma unroll
            for (int tt = 0; tt < 6; tt++) {
#pragma unroll
                for (int kc = 0; kc < 4; kc++) pin_h8(Bf[tt][kc]);
                pin_f(bias[tt]);
            }
            // produce gi for chunk 0
            if (lane == 0) wait_flag(fb + 0);
            {
                const _Float16* yrow = yb + (size_t)nl * H;
                h8 A0c[4];
#pragma unroll
                for (int kc = 0; kc < 4; kc++)
                    A0c[kc] = load_y0_h8(yrow + 32 * kc + 8 * q);
                f4v a0 = {0.f,0.f,0.f,0.f}, a1 = a0, a2 = a0, a3 = a0, a4 = a0, a5 = a0;
#pragma unroll
                for (int kc = 0; kc < 4; kc++) {
                    a0 = mfma16(A0c[kc], Bf[0][kc], a0);
                    a1 = mfma16(A0c[kc], Bf[1][kc], a1);
                    a2 = mfma16(A0c[kc], Bf[2][kc], a2);
                    a3 = mfma16(A0c[kc], Bf[3][kc], a3);
                    a4 = mfma16(A0c[kc], Bf[4][kc], a4);
                    a5 = mfma16(A0c[kc], Bf[5][kc], a5);
                }
                f4v accs[6] = {a0, a1, a2, a3, a4, a5};
                float* gp = &sGi[0][0][0][0];
#pragma unroll
                for (int tt = 0; tt < 6; tt++) {
                    const int n = 16 * (wv * 6 + tt) + nl;
                    const int g = n >> 7, jj = n & 127;
#pragma unroll
                    for (int r = 0; r < 4; r++)
                        gp[((4 * q + r) * 3 + g) * GIP + jj] = accs[tt][r] + bias[tt];
                }
            }
        }
        float hprev = 0.0f;
        __syncthreads();

        for (int t = 0; t < S; t++) {
            const int cur = t & 1;
            const int c   = t >> 4;
            const int tw  = t & (CH - 1);

            if (isRec) {
                const float gr = sGi[c & 1][tw][0][jr];
                const float gz = sGi[c & 1][tw][1][jr];
                const float gn = sGi[c & 1][tw][2][jr];
                const float4* hv = (const float4*)&sH1[cur][0];
                float ar = 0.f, az = 0.f, ahn = 0.f;
#pragma unroll
                for (int i = 0; i < 8; i++) {
                    const int ii = (i + 4 * mr) & 7;     // addr stagger
                    const float4 qv = hv[8 * mr + ii];
                    const h2 p0 = __builtin_bit_cast(h2, qv.x);
                    const h2 p1 = __builtin_bit_cast(h2, qv.y);
                    const h2 p2 = __builtin_bit_cast(h2, qv.z);
                    const h2 p3 = __builtin_bit_cast(h2, qv.w);
                    ar  = __builtin_amdgcn_fdot2(p0, wc[4*i+0],      ar,  false);
                    ar  = __builtin_amdgcn_fdot2(p1, wc[4*i+1],      ar,  false);
                    ar  = __builtin_amdgcn_fdot2(p2, wc[4*i+2],      ar,  false);
                    ar  = __builtin_amdgcn_fdot2(p3, wc[4*i+3],      ar,  false);
                    az  = __builtin_amdgcn_fdot2(p0, wc[32+4*i+0],   az,  false);
                    az  = __builtin_amdgcn_fdot2(p1, wc[32+4*i+1],   az,  false);
                    az  = __builtin_amdgcn_fdot2(p2, wc[32+4*i+2],   az,  false);
                    az  = __builtin_amdgcn_fdot2(p3, wc[32+4*i+3],   az,  false);
                    ahn = __builtin_amdgcn_fdot2(p0, wc[64+4*i+0],   ahn, false);
                    ahn = __builtin_amdgcn_fdot2(p1, wc[64+4*i+1],   ahn, false);
                    ahn = __builtin_amdgcn_fdot2(p2, wc[64+4*i+2],   ahn, false);
                    ahn = __builtin_amdgcn_fdot2(p3, wc[64+4*i+3],   ahn, false);
                }
                const float r  = sigf(pair_reduce(ar) + gr);
                const float z  = sigf(pair_reduce(az) + gz);
                const float n  = tanh_fast(gn + r * (pair_reduce(ahn) + b_hn));
                const float hn = n + z * (hprev - n);
                hprev = hn;
                if (mr == 0) {
                    sH1[cur ^ 1][jr]   = (_Float16)hn;
                    sHo[c & 1][tw][jr] = (_Float16)hn;
                }
            } else {
                if (tw == 0) {
                    // flush h1 chunk c-1 over the consumed y0 (4 KB, 256 thr x 2 uint2)
                    if (c >= 1) {
                        const int cp  = c - 1;
                        const int idx = tid - 256;
                        const uint2 v0 = ((const uint2*)&sHo[cp & 1][0][0])[idx];
                        const uint2 v1 = ((const uint2*)&sHo[cp & 1][0][0])[idx + 256];
                        ((uint2*)(yb + (size_t)cp * CH * H))[idx]       = v0;
                        ((uint2*)(yb + (size_t)cp * CH * H))[idx + 256] = v1;
                    }
                    // start producing gi for chunk c+1: wait + A prefetch
                    if (c + 1 < NCH) {
                        if (lane == 0) wait_flag(fb + (c + 1));
                        const _Float16* yr2 = yb + ((size_t)(c + 1) * CH + nl) * H;
#pragma unroll
                        for (int kc = 0; kc < 4; kc++)
                            Apre[kc] = load_y0_h8(yr2 + 32 * kc + 8 * q);
                    }
                } else if (tw == 1 && c + 1 < NCH) {
                    f4v a0 = {0.f,0.f,0.f,0.f}, a1 = a0, a2 = a0, a3 = a0, a4 = a0, a5 = a0;
#pragma unroll
                    for (int kc = 0; kc < 4; kc++) {
                        a0 = mfma16(Apre[kc], Bf[0][kc], a0);
                        a1 = mfma16(Apre[kc], Bf[1][kc], a1);
                        a2 = mfma16(Apre[kc], Bf[2][kc], a2);
                        a3 = mfma16(Apre[kc], Bf[3][kc], a3);
                        a4 = mfma16(Apre[kc], Bf[4][kc], a4);
                        a5 = mfma16(Apre[kc], Bf[5][kc], a5);
                    }
                    f4v accs[6] = {a0, a1, a2, a3, a4, a5};
                    float* gp = &sGi[(c + 1) & 1][0][0][0];
#pragma unroll
                    for (int tt = 0; tt < 6; tt++) {
                        const int n = 16 * (wv * 6 + tt) + nl;
                        const int g = n >> 7, jj = n & 127;
#pragma unroll
                        for (int r = 0; r < 4; r++)
                            gp[((4 * q + r) * 3 + g) * GIP + jj] = accs[tt][r] + bias[tt];
                    }
                }
            }
            __syncthreads();
        }
        // final h1 chunk flush (helpers; loop's last barrier made sHo visible)
        if (!isRec) {
            const int cp  = NCH - 1;
            const int idx = tid - 256;
            const uint2 v0 = ((const uint2*)&sHo[cp & 1][0][0])[idx];
            const uint2 v1 = ((const uint2*)&sHo[cp & 1][0][0])[idx + 256];
            ((uint2*)(yb + (size_t)cp * CH * H))[idx]       = v0;
            ((uint2*)(yb + (size_t)cp * CH * H))[idx + 256] = v1;
        }
    }
}

// ---------------------------------------------------------------------------
// MFMA MLP head. 512 blocks x 256 threads (4 independent waves, no barriers).
// ---------------------------------------------------------------------------
__global__ __launch_bounds__(256, 2)
void head_mfma(const _Float16* __restrict__ h1, const float* __restrict__ x,
               const float* __restrict__ w1, const float* __restrict__ b1,
               const float* __restrict__ w2, const float* __restrict__ b2,
               float* __restrict__ inc)
{
    const int wave = threadIdx.x >> 6;
    const int lane = threadIdx.x & 63;
    const int nl   = lane & 15;
    const int q    = lane >> 4;

    h8 Bf[4][5];
    float b1v[4], w2v[4];
#pragma unroll
    for (int t = 0; t < 4; t++) {
        const int n = 16 * t + nl;
        const float* wr = w1 + (size_t)n * F;
#pragma unroll
        for (int c = 0; c < 4; c++)
            Bf[t][c] = cvt8v(wr + 32 * c + 8 * q);
        if (q < 2) Bf[t][4] = cvt8v(wr + 128 + 8 * q);
        else { h8 z = {};
               Bf[t][4] = z; }
        b1v[t] = b1[n];
        w2v[t] = w2[n];
    }
    const float b2v = b2[0];

    const int gw = blockIdx.x * 4 + wave;

    for (int it = 0; it < 8; it++) {
        const int row0 = (gw * 8 + it) * 16;
        const int rm   = row0 + nl;

        const _Float16* hp = h1 + (size_t)rm * H;
        h8 A0 = *(const h8*)(hp + 8 * q);
        h8 A1 = *(const h8*)(hp + 32 + 8 * q);
        h8 A2 = *(const h8*)(hp + 64 + 8 * q);
        h8 A3 = *(const h8*)(hp + 96 + 8 * q);
        h8 A4;
        if (q < 2) A4 = cvt8v(x + (size_t)rm * NI + 8 * q);
        else { h8 z = {}; A4 = z; }

        f4v acc0 = {0.f,0.f,0.f,0.f}, acc1 = {0.f,0.f,0.f,0.f};
        f4v acc2 = {0.f,0.f,0.f,0.f}, acc3 = {0.f,0.f,0.f,0.f};
        acc0 = mfma16(A0, Bf[0][0], acc0); acc1 = mfma16(A0, Bf[1][0], acc1);
        acc2 = mfma16(A0, Bf[2][0], acc2); acc3 = mfma16(A0, Bf[3][0], acc3);
        acc0 = mfma16(A1, Bf[0][1], acc0); acc1 = mfma16(A1, Bf[1][1], acc1);
        acc2 = mfma16(A1, Bf[2][1], acc2); acc3 = mfma16(A1, Bf[3][1], acc3);
        acc0 = mfma16(A2, Bf[0][2], acc0); acc1 = mfma16(A2, Bf[1][2], acc1);
        acc2 = mfma16(A2, Bf[2][2], acc2); acc3 = mfma16(A2, Bf[3][2], acc3);
        acc0 = mfma16(A3, Bf[0][3], acc0); acc1 = mfma16(A3, Bf[1][3], acc1);
        acc2 = mfma16(A3, Bf[2][3], acc2); acc3 = mfma16(A3, Bf[3][3], acc3);
        acc0 = mfma16(A4, Bf[0][4], acc0); acc1 = mfma16(A4, Bf[1][4], acc1);
        acc2 = mfma16(A4, Bf[2][4], acc2); acc3 = mfma16(A4, Bf[3][4], acc3);

        float rs[4];
#pragma unroll
        for (int r = 0; r < 4; r++) {
            rs[r] = fmaxf(acc0[r] + b1v[0], 0.f) * w2v[0]
                  + fmaxf(acc1[r] + b1v[1], 0.f) * w2v[1]
                  + fmaxf(acc2[r] + b1v[2], 0.f) * w2v[2]
                  + fmaxf(acc3[r] + b1v[3], 0.f) * w2v[3];
        }
#pragma unroll
        for (int off = 1; off < 16; off <<= 1) {
#pragma unroll
            for (int r = 0; r < 4; r++)
                rs[r] += __shfl_xor(rs[r], off, 64);
        }
        if (nl == 0) {
            float4 o;
            o.x = tanh_fast(rs[0] + b2v) * 0.125f;
            o.y = tanh_fast(rs[1] + b2v) * 0.125f;
            o.z = tanh_fast(rs[2] + b2v) * 0.125f;
            o.w = tanh_fast(rs[3] + b2v) * 0.125f;
            *(float4*)(inc + row0 + 4 * q) = o;
        }
    }
}

// ---------------------------------------------------------------------------
// Inclusive cumsum over S per batch + initial offset. One block per batch.
// ---------------------------------------------------------------------------
__global__ __launch_bounds__(256)
void cumsum_kernel(const float* __restrict__ inc, const float* __restrict__ init,
                   float* __restrict__ out)
{
    __shared__ float sW[4];
    const int b = blockIdx.x;
    const int tid = threadIdx.x;
    const int lane = tid & 63;
    const int wid = tid >> 6;

    const float* ib = inc + (size_t)b * S;
    float v[16];
#pragma unroll
    for (int i = 0; i < 16; i++) v[i] = ib[tid * 16 + i];

    float run = 0.f;
#pragma unroll
    for (int i = 0; i < 16; i++) { run += v[i]; v[i] = run; }

    float t = run;
#pragma unroll
    for (int off = 1; off < 64; off <<= 1) {
        float u = __shfl_up(t, off, 64);
        if (lane >= off) t += u;
    }
    const float excl = t - run;
    if (lane == 63) sW[wid] = t;
    __syncthreads();

    float wo = 0.f;
#pragma unroll
    for (int w = 0; w < 4; w++) if (w < wid) wo += sW[w];

    const float prefix = wo + excl + init[0];
    float* ob = out + (size_t)b * S;
#pragma unroll
    for (int i = 0; i < 16; i++) ob[tid * 16 + i] = prefix + v[i];
}

// ---------------------------------------------------------------------------
extern "C" void kernel_launch(void* const* d_in, const int* in_sizes, int n_in,
                              void* d_out, int out_size, void* d_ws, size_t ws_size,
                              hipStream_t stream)
{
    (void)in_sizes; (void)n_in; (void)out_size; (void)ws_size;
    const float* x     = (const float*)d_in[0];
    const float* w_ih0 = (const float*)d_in[1];
    const float* w_hh0 = (const float*)d_in[2];
    const float* b_ih0 = (const float*)d_in[3];
    const float* b_hh0 = (const float*)d_in[4];
    const float* w_ih1 = (const float*)d_in[5];
    const float* w_hh1 = (const float*)d_in[6];
    const float* b_ih1 = (const float*)d_in[7];
    const float* b_hh1 = (const float*)d_in[8];
    const float* w1    = (const float*)d_in[9];
    const float* b1    = (const float*)d_in[10];
    const float* w2    = (const float*)d_in[11];
    const float* b2    = (const float*)d_in[12];
    const float* init  = (const float*)d_in[13];
    float* out = (float*)d_out;

    _Float16* hbuf = (_Float16*)d_ws;                                   // 64 MB fp16
    float* incbuf  = (float*)((char*)d_ws + (size_t)B * S * H * 2);     // 1 MB
    int* flags     = (int*)((char*)d_ws + (size_t)B * S * H * 2
                                        + (size_t)B * S * 4);           // 64 KB

    hipMemsetAsync(flags, 0, (size_t)B * NCH * sizeof(int), stream);

    hipLaunchKernelGGL(gru_pipe, dim3(2 * B), dim3(512), 0, stream,
                       x, w_ih0, w_hh0, b_ih0, b_hh0,
                       w_ih1, w_hh1, b_ih1, b_hh1, hbuf, flags);
    hipLaunchKernelGGL(head_mfma, dim3(512), dim3(256), 0, stream,
                       hbuf, x, w1, b1, w2, b2, incbuf);
    hipLaunchKernelGGL(cumsum_kernel, dim3(B), dim3(256), 0, stream,
                       incbuf, init, out);
}